// Round 2
// baseline (715.494 us; speedup 1.0000x reference)
//
#include <hip/hip_runtime.h>
#include <hip/hip_bf16.h>

// R-GCN restructured as: prep -> stage1 (14 small GEMMs) -> stage2 (select/delta)
// -> main split-K GEMM (K=16384 concat of 4 chunks) -> reduce (+L0).
// Inputs/outputs are FLOAT32 (per reference); bf16 only internally for MFMA.

typedef __bf16 bf16x8 __attribute__((ext_vector_type(8)));
typedef float floatx4 __attribute__((ext_vector_type(4)));
using bf16 = __hip_bfloat16;

#define LDK 72   // 64 + 8 pad (keeps 16B alignment, breaks LDS bank aliasing)

__device__ __forceinline__ float b2f(bf16 x){ return __bfloat162float(x); }
__device__ __forceinline__ bf16 f2b(float f){ return __float2bfloat16(f); }
__device__ __forceinline__ unsigned short f2bu(float f){
  bf16 h = __float2bfloat16(f); unsigned short u; __builtin_memcpy(&u,&h,2); return u;
}
__device__ __forceinline__ uint4 cvt8(float4 a, float4 b){
  unsigned short u[8] = {f2bu(a.x),f2bu(a.y),f2bu(a.z),f2bu(a.w),
                         f2bu(b.x),f2bu(b.y),f2bu(b.z),f2bu(b.w)};
  uint4 v; __builtin_memcpy(&v,u,16); return v;
}

// ---------------------------------------------------------------- prep ------
// scal layout: [r0m, r1m, nrmm, r0d, r1d, nrmd] each 4096 fp32.
// Sbuf: S01,S25,S34,S67 (256x256 fp32 each). bSbuf: matching bias sums (fp32).
__global__ void prep_kernel(const float* __restrict__ m_co_deg, const float* __restrict__ d_co_deg,
                            const float* __restrict__ m_d_degree, const float* __restrict__ d_m_degree,
                            const float* __restrict__ Wx, const float* __restrict__ bx,
                            float* __restrict__ scal, float* __restrict__ Sbuf, float* __restrict__ bSbuf)
{
  const int i = blockIdx.x*blockDim.x + threadIdx.x;
  if (i < 4096){
    scal[0*4096+i] = rsqrtf(m_co_deg[2*i]);
    scal[1*4096+i] = rsqrtf(m_co_deg[2*i+1]);
    scal[2*4096+i] = 0.5f / m_d_degree[i];
    scal[3*4096+i] = rsqrtf(d_co_deg[2*i]);
    scal[4*4096+i] = rsqrtf(d_co_deg[2*i+1]);
    scal[5*4096+i] = 0.5f / d_m_degree[i];
  }
  const int pa[4] = {0,2,3,6}, pb[4] = {1,5,4,7};
  if (i < 65536){
    #pragma unroll
    for (int s=0;s<4;s++)
      Sbuf[s*65536+i] = Wx[pa[s]*65536+i] + Wx[pb[s]*65536+i];
  }
  if (i < 256){
    #pragma unroll
    for (int s=0;s<4;s++)
      bSbuf[s*256+i] = bx[pa[s]*256+i] + bx[pb[s]*256+i];
  }
}

// -------------------------------------------------------------- stage 1 -----
// 14 problems (blockIdx.y): side = p/7 (0=m,1=d), widx = p%7.
//  widx 0: L0 = X@W0^T + b0            -> natural layout [node][feat], fp32
//  widx 1: B block0 = r0[c]*(X@W1^T+b) -> transposed [feat][node] into B*T col 0
//  widx 2: B block1 = r1[c]*(X@W2^T+b) -> transposed into B*T col 4096
//  widx 3..6: T_S = X@S^T + bS         -> transposed temps [feat][node]
// Mode T swaps MFMA operands (A=W, B=X) so the output lands transposed with
// both operands read in natural row-major [.][k] layout.
__global__ __launch_bounds__(256) void stage1_kernel(
    const float* __restrict__ feat, const float* __restrict__ Wm, const float* __restrict__ bm,
    const float* __restrict__ Wd, const float* __restrict__ bd,
    const float* __restrict__ Sbuf, const float* __restrict__ bSbuf, const float* __restrict__ scal,
    bf16* __restrict__ BmT, bf16* __restrict__ BdT, float* __restrict__ L0m, float* __restrict__ L0d,
    bf16* __restrict__ TmT, bf16* __restrict__ TdT)
{
  __shared__ __align__(16) bf16 As[128*LDK];
  __shared__ __align__(16) bf16 Bs[128*LDK];
  const int p = blockIdx.y;
  const int side = p / 7, widx = p % 7;
  const int bx_ = blockIdx.x;
  const bool modeT = (widx != 0);
  const float* X = feat + (size_t)side*(4096*256);
  const float* W = (widx<=2) ? ((side? Wd: Wm) + widx*65536) : (Sbuf + (widx-3)*65536);
  int rt, ct;
  if (!modeT){ rt = bx_>>1; ct = bx_&1; } else { rt = bx_&1; ct = bx_>>1; }
  const float* Amat = modeT ? W : X;
  const float* Bmat = modeT ? X : W;
  const int arow0 = rt*128, brow0 = ct*128;
  const int tid = threadIdx.x;
  const int lane = tid & 63, wv = tid>>6;
  const int wr = wv>>1, wc = wv&1, q = lane>>4, l15 = lane&15;

  floatx4 acc[4][4];
  #pragma unroll
  for (int i=0;i<4;i++)
    #pragma unroll
    for (int j=0;j<4;j++)
      #pragma unroll
      for (int r=0;r<4;r++) acc[i][j][r] = 0.f;

  for (int kt=0; kt<4; kt++){
    const int c0 = kt*64;
    __syncthreads();
    #pragma unroll
    for (int i=0;i<4;i++){
      const int id = tid + i*256;
      const int row = id>>3, kg = id&7;
      const float* ap = Amat + (size_t)(arow0+row)*256 + c0 + kg*8;
      const float* bp = Bmat + (size_t)(brow0+row)*256 + c0 + kg*8;
      float4 a0 = *(const float4*)ap, a1 = *(const float4*)(ap+4);
      float4 b0 = *(const float4*)bp, b1 = *(const float4*)(bp+4);
      *(uint4*)(&As[row*LDK + kg*8]) = cvt8(a0,a1);
      *(uint4*)(&Bs[row*LDK + kg*8]) = cvt8(b0,b1);
    }
    __syncthreads();
    #pragma unroll
    for (int ki=0; ki<2; ki++){
      bf16x8 af[4], bg[4];
      #pragma unroll
      for (int i=0;i<4;i++) af[i] = *(const bf16x8*)&As[(wr*64 + i*16 + l15)*LDK + ki*32 + q*8];
      #pragma unroll
      for (int j=0;j<4;j++) bg[j] = *(const bf16x8*)&Bs[(wc*64 + j*16 + l15)*LDK + ki*32 + q*8];
      #pragma unroll
      for (int i=0;i<4;i++)
        #pragma unroll
        for (int j=0;j<4;j++)
          acc[i][j] = __builtin_amdgcn_mfma_f32_16x16x32_bf16(af[i], bg[j], acc[i][j], 0,0,0);
    }
  }

  const float* bias = (widx<=2) ? ((side? bd: bm) + widx*256) : (bSbuf + (widx-3)*256);
  float* outF = nullptr; bf16* outB = nullptr; int pitch = 256; const float* scl = nullptr;
  if (widx==0){ outF = side? L0d: L0m; pitch = 256; }
  else if (widx==1){ outB = side? BdT: BmT; pitch = 16384; scl = scal + side*12288; }
  else if (widx==2){ outB = (side? BdT: BmT) + 4096; pitch = 16384; scl = scal + side*12288 + 4096; }
  else { outB = (side? TdT: TmT) + (widx-3)*(256*4096); pitch = 4096; }

  #pragma unroll
  for (int i=0;i<4;i++){
    #pragma unroll
    for (int j=0;j<4;j++){
      const int gcol = brow0 + wc*64 + j*16 + l15;
      #pragma unroll
      for (int r=0;r<4;r++){
        const int grow = arow0 + wr*64 + i*16 + q*4 + r;
        float v = acc[i][j][r];
        const int nidx = modeT ? grow : gcol;       // feature index for the bias
        v += bias[nidx];
        if (scl) v *= scl[gcol];
        if (outF) outF[(size_t)grow*pitch + gcol] = v;
        else      outB[(size_t)grow*pitch + gcol] = f2b(v);
      }
    }
  }
}

// -------------------------------------------------------------- stage 2 -----
// Build cross-blocks of B*T:  block2 = V0 (a=0 selection), block3 = V1 - V0.
// T temp order: [S01, S25, S34, S67].
__global__ void stage2_kernel(const bf16* __restrict__ TmT, const bf16* __restrict__ TdT,
                              const int* __restrict__ central_m, const int* __restrict__ central_d,
                              bf16* __restrict__ BmT, bf16* __restrict__ BdT)
{
  const int idx = blockIdx.x*blockDim.x + threadIdx.x;   // [0, 2*256*4096)
  const int side = idx >> 20;
  const int rem = idx & 1048575;
  const int n = rem >> 12;
  const int c = rem & 4095;
  const bf16* T = side ? TmT : TdT;     // side0 builds BmT whose src feats are d
  const int* cen = side ? central_m : central_d;
  bf16* B = side ? BdT : BmT;
  const bool cc = cen[c] != 0;
  int v0i, v1i;
  if (!side){ v0i = cc ? 2 : 3; v1i = cc ? 0 : 1; }   // md: a0: S34/S67, a1: S01/S25
  else      { v0i = cc ? 1 : 3; v1i = cc ? 0 : 2; }   // dm: a0: S25/S67, a1: S01/S34
  const float v0 = b2f(T[(size_t)v0i*1048576 + (size_t)n*4096 + c]);
  const float v1 = b2f(T[(size_t)v1i*1048576 + (size_t)n*4096 + c]);
  B[(size_t)n*16384 + 8192 + c]  = f2b(v0);
  B[(size_t)n*16384 + 12288 + c] = f2b(v1 - v0);
}

// ------------------------------------------------------------ main GEMM -----
// partial[chunk][r][n] = sum_c Ahat[r, chunk*4096+c] * Bhat[chunk*4096+c][n]
// Ahat generated on the fly from co / bigraph (fp32) + row scalars.
__global__ __launch_bounds__(256) void gemm_kernel(
    const float* __restrict__ bigraph, const float* __restrict__ m_co, const float* __restrict__ d_co,
    const int* __restrict__ central_m, const int* __restrict__ central_d,
    const float* __restrict__ scal, const bf16* __restrict__ BmT, const bf16* __restrict__ BdT,
    float* __restrict__ partial)
{
  __shared__ __align__(16) bf16 As[128*LDK];
  __shared__ __align__(16) bf16 Bs[128*LDK];
  const int tile = blockIdx.x;    // [0,128): rt = tile>>1 (row tile), ct = tile&1 (col tile)
  const int chunk = blockIdx.y;   // [0,4)
  const int rt = tile>>1, ct = tile&1;
  const int rowbase = rt*128;
  const int side = (rowbase >= 4096) ? 1 : 0;
  const int rloc0 = rowbase & 4095;
  const bf16* BT = side? BdT : BmT;
  const float* sc = scal + side*12288;     // [r0, r1, nrm]
  const int* cen = side? central_d : central_m;
  const float* co = side? d_co : m_co;
  const int n0 = ct*128;
  const int tid = threadIdx.x;
  const int lane = tid&63, wv = tid>>6, wr = wv>>1, wc = wv&1, q = lane>>4, l15 = lane&15;

  floatx4 acc[4][4];
  #pragma unroll
  for (int i=0;i<4;i++)
    #pragma unroll
    for (int j=0;j<4;j++)
      #pragma unroll
      for (int r=0;r<4;r++) acc[i][j][r] = 0.f;

  for (int kt=0; kt<64; kt++){
    const int c0 = kt*64;
    __syncthreads();
    #pragma unroll
    for (int i=0;i<4;i++){
      const int id = tid + i*256;
      const int row = id>>3, kg = id&7;
      const int gc = c0 + kg*8;
      const int rl = rloc0 + row;
      uint4 vb = *(const uint4*)(BT + (size_t)(n0+row)*16384 + chunk*4096 + gc);
      *(uint4*)(&Bs[row*LDK + kg*8]) = vb;
      unsigned short outv[8];
      if (chunk < 2){
        const float* cp = co + (size_t)rl*4096 + gc;
        float4 ca = *(const float4*)cp, cb = *(const float4*)(cp+4);
        const float cv[8] = {ca.x,ca.y,ca.z,ca.w,cb.x,cb.y,cb.z,cb.w};
        const unsigned short rvb = f2bu(sc[chunk*4096 + rl]);
        #pragma unroll
        for (int jj=0;jj<8;jj++){
          const bool nz = (cv[jj] != 0.0f);
          const bool sel = (chunk==0) ? nz : !nz;
          outv[jj] = (sel && (gc+jj != rl)) ? rvb : (unsigned short)0;
        }
      } else {
        const float* srcp = side ? (bigraph + (size_t)(4096+rl)*8192 + gc)
                                 : (bigraph + (size_t)rl*8192 + 4096 + gc);
        float4 va = *(const float4*)srcp, vb2 = *(const float4*)(srcp+4);
        const float av[8] = {va.x,va.y,va.z,va.w,vb2.x,vb2.y,vb2.z,vb2.w};
        float s = sc[8192 + rl];
        if (chunk==3 && cen[rl]==0) s = 0.f;
        #pragma unroll
        for (int jj=0;jj<8;jj++) outv[jj] = f2bu(av[jj] * s);
      }
      uint4 vout; __builtin_memcpy(&vout, outv, 16);
      *(uint4*)(&As[row*LDK + kg*8]) = vout;
    }
    __syncthreads();
    #pragma unroll
    for (int ki=0; ki<2; ki++){
      bf16x8 af[4], bg[4];
      #pragma unroll
      for (int i=0;i<4;i++) af[i] = *(const bf16x8*)&As[(wr*64 + i*16 + l15)*LDK + ki*32 + q*8];
      #pragma unroll
      for (int j=0;j<4;j++) bg[j] = *(const bf16x8*)&Bs[(wc*64 + j*16 + l15)*LDK + ki*32 + q*8];
      #pragma unroll
      for (int i=0;i<4;i++)
        #pragma unroll
        for (int j=0;j<4;j++)
          acc[i][j] = __builtin_amdgcn_mfma_f32_16x16x32_bf16(af[i], bg[j], acc[i][j], 0,0,0);
    }
  }

  float* pbase = partial + (size_t)chunk*2097152;
  #pragma unroll
  for (int i=0;i<4;i++){
    #pragma unroll
    for (int j=0;j<4;j++){
      const int gcol = n0 + wc*64 + j*16 + l15;
      #pragma unroll
      for (int r=0;r<4;r++){
        const int grow = rowbase + wr*64 + i*16 + q*4 + r;
        pbase[(size_t)grow*256 + gcol] = acc[i][j][r];
      }
    }
  }
}

// -------------------------------------------------------------- reduce ------
__global__ void reduce_kernel(const float* __restrict__ partial, const float* __restrict__ L0m,
                              const float* __restrict__ L0d, float* __restrict__ out)
{
  const int idx = blockIdx.x*blockDim.x + threadIdx.x;   // [0, 524288)
  const int r = idx >> 6;
  const int n4 = (idx & 63) << 2;
  const size_t base = (size_t)r*256 + n4;
  float s0=0.f, s1=0.f, s2=0.f, s3=0.f;
  #pragma unroll
  for (int t=0;t<4;t++){
    const float4 pv = *(const float4*)(partial + (size_t)t*2097152 + base);
    s0 += pv.x; s1 += pv.y; s2 += pv.z; s3 += pv.w;
  }
  const float* L0row = (r < 4096) ? (L0m + (size_t)r*256) : (L0d + (size_t)(r-4096)*256);
  const float4 lv = *(const float4*)(L0row + n4);
  float4 o; o.x = s0+lv.x; o.y = s1+lv.y; o.z = s2+lv.z; o.w = s3+lv.w;
  *(float4*)(out + base) = o;
}

// ---------------------------------------------------------------------------
extern "C" void kernel_launch(void* const* d_in, const int* in_sizes, int n_in,
                              void* d_out, int out_size, void* d_ws, size_t ws_size,
                              hipStream_t stream)
{
  (void)in_sizes; (void)n_in; (void)out_size; (void)ws_size;
  const float* m_d_feat   = (const float*)d_in[0];
  const float* bigraph    = (const float*)d_in[1];
  const float* m_co       = (const float*)d_in[2];
  const float* d_co       = (const float*)d_in[3];
  const float* m_co_deg   = (const float*)d_in[4];
  const float* d_co_deg   = (const float*)d_in[5];
  const float* m_d_degree = (const float*)d_in[6];
  const float* d_m_degree = (const float*)d_in[7];
  const float* Wm = (const float*)d_in[8];
  const float* bm = (const float*)d_in[9];
  const float* Wd = (const float*)d_in[10];
  const float* bd = (const float*)d_in[11];
  const float* Wx = (const float*)d_in[12];
  const float* bx = (const float*)d_in[13];
  const int* central_m = (const int*)d_in[14];
  const int* central_d = (const int*)d_in[15];

  char* ws = (char*)d_ws;
  bf16*  BmT   = (bf16*) (ws + 0);          // [256][16384] bf16
  bf16*  BdT   = (bf16*) (ws + 8388608);
  float* L0m   = (float*)(ws + 16777216);   // [4096][256] fp32
  float* L0d   = (float*)(ws + 20971520);
  float* Sbuf  = (float*)(ws + 25165824);   // 4 x [256][256] fp32
  float* bSbuf = (float*)(ws + 26214400);
  float* scal  = (float*)(ws + 26218496);   // 6 x 4096 fp32
  bf16*  TmT   = (bf16*) (ws + 26316800);   // 4 x [256][4096] bf16
  bf16*  TdT   = (bf16*) (ws + 34705408);
  float* partial = (float*)(ws + 26316800); // 4 x [8192][256] fp32 — ALIASES T (dead after stage2)

  prep_kernel<<<256, 256, 0, stream>>>(m_co_deg, d_co_deg, m_d_degree, d_m_degree,
                                       Wx, bx, scal, Sbuf, bSbuf);
  stage1_kernel<<<dim3(64,14), 256, 0, stream>>>(m_d_feat, Wm, bm, Wd, bd, Sbuf, bSbuf, scal,
                                                 BmT, BdT, L0m, L0d, TmT, TdT);
  stage2_kernel<<<8192, 256, 0, stream>>>(TmT, TdT, central_m, central_d, BmT, BdT);
  gemm_kernel<<<dim3(128,4), 256, 0, stream>>>(bigraph, m_co, d_co, central_m, central_d,
                                               scal, BmT, BdT, partial);
  reduce_kernel<<<2048, 256, 0, stream>>>(partial, L0m, L0d, (float*)d_out);
}

// Round 4
// 597.956 us; speedup vs baseline: 1.1966x; 1.1966x over previous
//
#include <hip/hip_runtime.h>
#include <hip/hip_bf16.h>

// R-GCN v3.1: algebraic fusion (non-co = J - diag - co) collapses the K=16384
// split into 4 uniform dual-group GEMMs sharing A-tiles:
//   H(s): C = M'(s) . [B0|B1],  B0=r0.L1^T, B1=r1.L2^T   (M' = offdiag co mask)
//   X(s): C = assoc(s) . [V0|V1-V0]
// Row scales, the rank-1 colsum term, and the diag correction move to epilogue.
// gemm: async global_load_lds B staging, XOR-swizzled LDS, split-K=2, atomics.
// v3.1 fix: zero_kernel offset was scaled twice -> OOB writes past workspace.

typedef __bf16 bf16x8 __attribute__((ext_vector_type(8)));
typedef float floatx4 __attribute__((ext_vector_type(4)));
using bf16 = __hip_bfloat16;

#define LDK 72   // stage1 LDS pad

__device__ __forceinline__ float b2f(bf16 x){ return __bfloat162float(x); }
__device__ __forceinline__ bf16 f2b(float f){ return __float2bfloat16(f); }
__device__ __forceinline__ float rawb2f(unsigned short u){
  unsigned int x = ((unsigned int)u) << 16; float f; __builtin_memcpy(&f,&x,4); return f;
}
__device__ __forceinline__ unsigned short f2bu(float f){
  bf16 h = __float2bfloat16(f); unsigned short u; __builtin_memcpy(&u,&h,2); return u;
}
__device__ __forceinline__ uint4 cvt8(float4 a, float4 b){
  unsigned short u[8] = {f2bu(a.x),f2bu(a.y),f2bu(a.z),f2bu(a.w),
                         f2bu(b.x),f2bu(b.y),f2bu(b.z),f2bu(b.w)};
  uint4 v; __builtin_memcpy(&v,u,16); return v;
}
// async global->LDS, 16B per lane; lds dest = wave-uniform base + lane*16
__device__ __forceinline__ void async_ld16(const void* gp, void* lp){
  typedef __attribute__((address_space(1))) const unsigned int GU;
  typedef __attribute__((address_space(3))) unsigned int LU;
  __builtin_amdgcn_global_load_lds((GU*)(unsigned long long)gp,
                                   (LU*)(unsigned int)(unsigned long long)lp,
                                   16, 0, 0);
}

// ---------------------------------------------------------------- prep ------
__global__ void prep_kernel(const float* __restrict__ m_co_deg, const float* __restrict__ d_co_deg,
                            const float* __restrict__ m_d_degree, const float* __restrict__ d_m_degree,
                            const float* __restrict__ Wx, const float* __restrict__ bx,
                            float* __restrict__ scal, float* __restrict__ Sbuf, float* __restrict__ bSbuf)
{
  const int i = blockIdx.x*blockDim.x + threadIdx.x;
  if (i < 4096){
    scal[0*4096+i] = rsqrtf(m_co_deg[2*i]);
    scal[1*4096+i] = rsqrtf(m_co_deg[2*i+1]);
    scal[2*4096+i] = 0.5f / m_d_degree[i];
    scal[3*4096+i] = rsqrtf(d_co_deg[2*i]);
    scal[4*4096+i] = rsqrtf(d_co_deg[2*i+1]);
    scal[5*4096+i] = 0.5f / d_m_degree[i];
  }
  const int pa[4] = {0,2,3,6}, pb[4] = {1,5,4,7};
  if (i < 65536){
    #pragma unroll
    for (int s=0;s<4;s++)
      Sbuf[s*65536+i] = Wx[pa[s]*65536+i] + Wx[pb[s]*65536+i];
  }
  if (i < 256){
    #pragma unroll
    for (int s=0;s<4;s++)
      bSbuf[s*256+i] = bx[pa[s]*256+i] + bx[pb[s]*256+i];
  }
}

// -------------------------------------------------------------- stage 1 -----
// 16 problems: side = p>>3, widx = p&7.
//  widx0: L0 = X@W0^T+b0 natural fp32 [4096][256]
//  widx7: L2nat = X@W2^T+b2 natural fp32 [4096][256]
//  widx1: BH rows 0-255   = (r0[c] * (X@W1^T+b1))^T   bf16 [512][4096]
//  widx2: BH rows 256-511 = (r1[c] * (X@W2^T+b2))^T
//  widx3-6: T temps = (X@S^T+bS)^T  bf16 4x[256][4096]
__global__ __launch_bounds__(256) void stage1_kernel(
    const float* __restrict__ feat, const float* __restrict__ Wm, const float* __restrict__ bm,
    const float* __restrict__ Wd, const float* __restrict__ bd,
    const float* __restrict__ Sbuf, const float* __restrict__ bSbuf, const float* __restrict__ scal,
    bf16* __restrict__ BHm, bf16* __restrict__ BHd,
    float* __restrict__ L0m, float* __restrict__ L0d,
    float* __restrict__ L2nm, float* __restrict__ L2nd,
    bf16* __restrict__ Tm, bf16* __restrict__ Td)
{
  __shared__ __align__(16) bf16 As[128*LDK];
  __shared__ __align__(16) bf16 Bs[128*LDK];
  const int p = blockIdx.y;
  const int side = p >> 3, widx = p & 7;
  const int bx_ = blockIdx.x;
  const bool modeT = (widx != 0 && widx != 7);
  const float* X = feat + (size_t)side*(4096*256);
  const float* Wb = side ? Wd : Wm;
  const float* W = (widx==0) ? Wb : (widx==7) ? (Wb + 2*65536)
                 : (widx<=2) ? (Wb + widx*65536) : (Sbuf + (widx-3)*65536);
  int rt, ct;
  if (!modeT){ rt = bx_>>1; ct = bx_&1; } else { rt = bx_&1; ct = bx_>>1; }
  const float* Amat = modeT ? W : X;
  const float* Bmat = modeT ? X : W;
  const int arow0 = rt*128, brow0 = ct*128;
  const int tid = threadIdx.x;
  const int lane = tid & 63, wv = tid>>6;
  const int wr = wv>>1, wc = wv&1, q = lane>>4, l15 = lane&15;

  floatx4 acc[4][4];
  #pragma unroll
  for (int i=0;i<4;i++)
    #pragma unroll
    for (int j=0;j<4;j++)
      #pragma unroll
      for (int r=0;r<4;r++) acc[i][j][r] = 0.f;

  for (int kt=0; kt<4; kt++){
    const int c0 = kt*64;
    __syncthreads();
    #pragma unroll
    for (int i=0;i<4;i++){
      const int id = tid + i*256;
      const int row = id>>3, kg = id&7;
      const float* ap = Amat + (size_t)(arow0+row)*256 + c0 + kg*8;
      const float* bp = Bmat + (size_t)(brow0+row)*256 + c0 + kg*8;
      float4 a0 = *(const float4*)ap, a1 = *(const float4*)(ap+4);
      float4 b0 = *(const float4*)bp, b1 = *(const float4*)(bp+4);
      *(uint4*)(&As[row*LDK + kg*8]) = cvt8(a0,a1);
      *(uint4*)(&Bs[row*LDK + kg*8]) = cvt8(b0,b1);
    }
    __syncthreads();
    #pragma unroll
    for (int ki=0; ki<2; ki++){
      bf16x8 af[4], bg[4];
      #pragma unroll
      for (int i=0;i<4;i++) af[i] = *(const bf16x8*)&As[(wr*64 + i*16 + l15)*LDK + ki*32 + q*8];
      #pragma unroll
      for (int j=0;j<4;j++) bg[j] = *(const bf16x8*)&Bs[(wc*64 + j*16 + l15)*LDK + ki*32 + q*8];
      #pragma unroll
      for (int i=0;i<4;i++)
        #pragma unroll
        for (int j=0;j<4;j++)
          acc[i][j] = __builtin_amdgcn_mfma_f32_16x16x32_bf16(af[i], bg[j], acc[i][j], 0,0,0);
    }
  }

  const float* bb = side ? bd : bm;
  const float* bias = (widx==0) ? bb : (widx==7) ? (bb + 512)
                    : (widx<=2) ? (bb + widx*256) : (bSbuf + (widx-3)*256);
  float* outF = nullptr; bf16* outB = nullptr; int pitch = 256; const float* scl = nullptr;
  if (widx==0){ outF = side? L0d : L0m; }
  else if (widx==7){ outF = side? L2nd : L2nm; }
  else if (widx==1){ outB = side? BHd : BHm; pitch = 4096; scl = scal + side*12288; }
  else if (widx==2){ outB = (side? BHd : BHm) + 256*4096; pitch = 4096; scl = scal + side*12288 + 4096; }
  else { outB = (side? Td : Tm) + (widx-3)*(256*4096); pitch = 4096; }

  #pragma unroll
  for (int i=0;i<4;i++){
    #pragma unroll
    for (int j=0;j<4;j++){
      const int gcol = brow0 + wc*64 + j*16 + l15;
      #pragma unroll
      for (int r=0;r<4;r++){
        const int grow = arow0 + wr*64 + i*16 + q*4 + r;
        float v = acc[i][j][r];
        const int nidx = modeT ? grow : gcol;
        v += bias[nidx];
        if (scl) v *= scl[gcol];
        if (outF) outF[(size_t)grow*pitch + gcol] = v;
        else      outB[(size_t)grow*pitch + gcol] = f2b(v);
      }
    }
  }
}

// -------------------------------------------------------------- stage 2 -----
// BX(oside)[n][c] = V0sel, BX[256+n][c] = V1sel - V0sel. T order [S01,S25,S34,S67].
__global__ void stage2_kernel(const bf16* __restrict__ Tm, const bf16* __restrict__ Td,
                              const int* __restrict__ central_m, const int* __restrict__ central_d,
                              bf16* __restrict__ BXm, bf16* __restrict__ BXd)
{
  const int idx = blockIdx.x*blockDim.x + threadIdx.x;   // [0, 2*256*4096)
  const int oside = idx >> 20;
  const int rem = idx & 1048575;
  const int n = rem >> 12;
  const int c = rem & 4095;
  const bf16* T = oside ? Tm : Td;                 // source feats = opposite side
  const int* cen = oside ? central_m : central_d;  // column centrality = source side
  bf16* B = oside ? BXd : BXm;
  const bool cc = cen[c] != 0;
  int v0i, v1i;
  if (!oside){ v0i = cc ? 2 : 3; v1i = cc ? 0 : 1; }   // md: V0 = S34/S67, V1 = S01/S25
  else       { v0i = cc ? 1 : 3; v1i = cc ? 0 : 2; }   // dm: V0 = S25/S67, V1 = S01/S34
  const float v0 = b2f(T[(size_t)v0i*1048576 + (size_t)n*4096 + c]);
  const float v1 = b2f(T[(size_t)v1i*1048576 + (size_t)n*4096 + c]);
  B[(size_t)n*4096 + c]         = f2b(v0);
  B[(size_t)(256+n)*4096 + c]   = f2b(v1 - v0);
}

// -------------------------------------------------------------- colsum ------
// Scol[s][n] = sum_c BH(s)[256+n][c]   (the rank-1 J-term of the non-co mask)
__global__ void colsum_kernel(const bf16* __restrict__ BHm, const bf16* __restrict__ BHd,
                              float* __restrict__ Scol)
{
  const int b = blockIdx.x;          // [0,512)
  const int sd = b >> 8, n = b & 255;
  const int lane = threadIdx.x;      // 64
  const bf16* rowp = (sd ? BHd : BHm) + (size_t)(256+n)*4096;
  float s = 0.f;
  #pragma unroll
  for (int t=0;t<8;t++){
    const uint4 v = *(const uint4*)(rowp + t*512 + lane*8);
    unsigned short u[8]; __builtin_memcpy(u,&v,16);
    #pragma unroll
    for (int jj=0;jj<8;jj++) s += rawb2f(u[jj]);
  }
  #pragma unroll
  for (int off=32; off>0; off>>=1) s += __shfl_down(s, off);
  if (lane==0) Scol[sd*256 + n] = s;
}

// ---------------------------------------------------------------- zero ------
// partial = 4,194,304 floats = 1,048,576 float4. 262144 threads x 4 float4.
__global__ void zero_kernel(float* __restrict__ p)
{
  const size_t idx = (size_t)blockIdx.x*blockDim.x + threadIdx.x;   // [0, 262144)
  float4 z = {0.f,0.f,0.f,0.f};
  #pragma unroll
  for (int t=0;t<4;t++) *(float4*)(p + (idx + (size_t)t*262144)*4) = z;
}

// ------------------------------------------------------------ main GEMM -----
// 512 blocks: bid -> seg(2) x nt(2) x mt(32) x p(4).
// p0/p1 = H(m/d): A = offdiag co mask (binary). p2/p3 = X(m/d): A = assoc raw.
// Dual accumulators share the A tile (B group0 rows n, group1 rows 256+n).
// Epilogue applies row scales and atomicAdds combined result into partial[p].
__global__ __launch_bounds__(256,2) void gemm_kernel(
    const float* __restrict__ bigraph, const float* __restrict__ m_co, const float* __restrict__ d_co,
    const int* __restrict__ central_m, const int* __restrict__ central_d,
    const float* __restrict__ scal,
    const bf16* __restrict__ BHm, const bf16* __restrict__ BHd,
    const bf16* __restrict__ BXm, const bf16* __restrict__ BXd,
    float* __restrict__ partial)
{
  __shared__ __align__(16) bf16 As[8192];       // 128 x 64, xor-swizzled
  __shared__ __align__(16) bf16 Bs[2][8192];    // 2 groups x 128 x 64, xor-swizzled
  const int bid = blockIdx.x;
  const int seg = bid & 1, nt = (bid>>1)&1, mt = (bid>>2)&31, p = bid>>7;
  const int s = p & 1;
  const bool maskmode = (p < 2);
  const int k0 = seg*2048;
  const int rowbase = mt*128;
  const int n0 = nt*128;
  const float* Asrc; int apitch; int acoff;
  if (p==0){ Asrc = m_co; apitch = 4096; acoff = 0; }
  else if (p==1){ Asrc = d_co; apitch = 4096; acoff = 0; }
  else if (p==2){ Asrc = bigraph; apitch = 8192; acoff = 4096; }
  else { Asrc = bigraph + (size_t)4096*8192; apitch = 8192; acoff = 0; }
  const bf16* B0 = (p==0) ? BHm : (p==1) ? BHd : (p==2) ? BXm : BXd;

  const int tid = threadIdx.x;
  const int lane = tid&63, wv = tid>>6, wr = wv>>1, wc = wv&1, q = lane>>4, l15 = lane&15;

  floatx4 acc0[4][4], acc1[4][4];
  #pragma unroll
  for (int i=0;i<4;i++)
    #pragma unroll
    for (int j=0;j<4;j++)
      #pragma unroll
      for (int r=0;r<4;r++){ acc0[i][j][r] = 0.f; acc1[i][j][r] = 0.f; }

  for (int kt=0; kt<32; kt++){
    const int kkg = k0 + kt*64;
    // ---- B staging: async 16B, xor-swizzled chunks
    #pragma unroll
    for (int g2=0; g2<2; g2++){
      #pragma unroll
      for (int j=0;j<4;j++){
        const int chunk = wv*256 + j*64 + lane;
        const int row = chunk >> 3, sg = chunk & 7;
        const int gg = sg ^ (row & 7);
        const bf16* gp = B0 + (size_t)(g2*256 + n0 + row)*4096 + kkg + gg*8;
        async_ld16(gp, &Bs[g2][(wv*256 + j*64)*8]);
      }
    }
    // ---- A staging: generate from fp32 source, contiguous b128 writes
    #pragma unroll
    for (int i=0;i<4;i++){
      const int chunk = i*256 + tid;
      const int row = chunk >> 3, sg = chunk & 7;
      const int g = sg ^ (row & 7);
      const int gr = rowbase + row;
      const float* ap = Asrc + (size_t)gr*apitch + acoff + kkg + g*8;
      float4 a0 = *(const float4*)ap, a1 = *(const float4*)(ap+4);
      const float av[8] = {a0.x,a0.y,a0.z,a0.w,a1.x,a1.y,a1.z,a1.w};
      unsigned short u[8];
      if (maskmode){
        const int cbase = kkg + g*8;
        #pragma unroll
        for (int jj=0;jj<8;jj++)
          u[jj] = (av[jj]!=0.0f && (cbase+jj)!=gr) ? (unsigned short)0x3F80 : (unsigned short)0;
      } else {
        #pragma unroll
        for (int jj=0;jj<8;jj++) u[jj] = f2bu(av[jj]);
      }
      uint4 w4; __builtin_memcpy(&w4,u,16);
      *(uint4*)(&As[chunk*8]) = w4;
    }
    __syncthreads();
    // ---- compute: dual-group MFMA, A frags shared
    #pragma unroll
    for (int ki=0; ki<2; ki++){
      bf16x8 af[4], b0f[4], b1f[4];
      #pragma unroll
      for (int i=0;i<4;i++){
        const int ra = wr*64 + i*16 + l15;
        af[i] = *(const bf16x8*)&As[ra*64 + ((ki*4+q)^(ra&7))*8];
      }
      #pragma unroll
      for (int j=0;j<4;j++){
        const int rb = wc*64 + j*16 + l15;
        const int off = rb*64 + ((ki*4+q)^(rb&7))*8;
        b0f[j] = *(const bf16x8*)&Bs[0][off];
        b1f[j] = *(const bf16x8*)&Bs[1][off];
      }
      #pragma unroll
      for (int i=0;i<4;i++)
        #pragma unroll
        for (int j=0;j<4;j++){
          acc0[i][j] = __builtin_amdgcn_mfma_f32_16x16x32_bf16(af[i], b0f[j], acc0[i][j], 0,0,0);
          acc1[i][j] = __builtin_amdgcn_mfma_f32_16x16x32_bf16(af[i], b1f[j], acc1[i][j], 0,0,0);
        }
    }
    __syncthreads();
  }

  // ---- epilogue: combine groups with row scales, atomicAdd into partial[p]
  const float* scS = scal + (size_t)s*12288;
  const int* cenR = s ? central_d : central_m;
  float* pb = partial + (size_t)p*4096*256;
  #pragma unroll
  for (int i=0;i<4;i++){
    #pragma unroll
    for (int r_=0;r_<4;r_++){
      const int rl = rowbase + wr*64 + i*16 + q*4 + r_;
      float w0, w1;
      if (maskmode){ w0 = scS[rl]; w1 = -scS[4096+rl]; }
      else { const float nr = scS[8192+rl]; w0 = nr; w1 = cenR[rl] ? nr : 0.f; }
      #pragma unroll
      for (int j=0;j<4;j++){
        const int gcol = n0 + wc*64 + j*16 + l15;
        atomicAdd(&pb[(size_t)rl*256 + gcol], w0*acc0[i][j][r_] + w1*acc1[i][j][r_]);
      }
    }
  }
}

// -------------------------------------------------------------- reduce ------
// out[r][n] = L0 + pH + pX + r1*Scol[n] - r1^2*L2nat
__global__ void reduce_kernel(const float* __restrict__ partial,
                              const float* __restrict__ L0m, const float* __restrict__ L0d,
                              const float* __restrict__ L2nm, const float* __restrict__ L2nd,
                              const float* __restrict__ Scol, const float* __restrict__ scal,
                              float* __restrict__ out)
{
  const int idx = blockIdx.x*blockDim.x + threadIdx.x;   // [0, 524288)
  const int r = idx >> 6;
  const int n4 = (idx & 63) << 2;
  const int s = r >> 12;            // 0: m, 1: d
  const int rl = r & 4095;
  const float r1 = scal[s*12288 + 4096 + rl];
  const size_t rb = (size_t)rl*256 + n4;
  const float4 l0 = *(const float4*)((s? L0d : L0m) + rb);
  const float4 l2 = *(const float4*)((s? L2nd : L2nm) + rb);
  const float4 sc = *(const float4*)(Scol + s*256 + n4);
  const float4 ph = *(const float4*)(partial + (size_t)s*1048576 + rb);
  const float4 px = *(const float4*)(partial + (size_t)(2+s)*1048576 + rb);
  const float r1sq = r1*r1;
  float4 o;
  o.x = l0.x + ph.x + px.x + r1*sc.x - r1sq*l2.x;
  o.y = l0.y + ph.y + px.y + r1*sc.y - r1sq*l2.y;
  o.z = l0.z + ph.z + px.z + r1*sc.z - r1sq*l2.z;
  o.w = l0.w + ph.w + px.w + r1*sc.w - r1sq*l2.w;
  *(float4*)(out + (size_t)r*256 + n4) = o;
}

// ---------------------------------------------------------------------------
extern "C" void kernel_launch(void* const* d_in, const int* in_sizes, int n_in,
                              void* d_out, int out_size, void* d_ws, size_t ws_size,
                              hipStream_t stream)
{
  (void)in_sizes; (void)n_in; (void)out_size; (void)ws_size;
  const float* m_d_feat   = (const float*)d_in[0];
  const float* bigraph    = (const float*)d_in[1];
  const float* m_co       = (const float*)d_in[2];
  const float* d_co       = (const float*)d_in[3];
  const float* m_co_deg   = (const float*)d_in[4];
  const float* d_co_deg   = (const float*)d_in[5];
  const float* m_d_degree = (const float*)d_in[6];
  const float* d_m_degree = (const float*)d_in[7];
  const float* Wm = (const float*)d_in[8];
  const float* bm = (const float*)d_in[9];
  const float* Wd = (const float*)d_in[10];
  const float* bd = (const float*)d_in[11];
  const float* Wx = (const float*)d_in[12];
  const float* bx = (const float*)d_in[13];
  const int* central_m = (const int*)d_in[14];
  const int* central_d = (const int*)d_in[15];

  char* ws = (char*)d_ws;
  bf16*  BHm  = (bf16*) (ws + 0);          // [512][4096] bf16 = 4 MB
  bf16*  BHd  = (bf16*) (ws + 4194304);
  bf16*  BXm  = (bf16*) (ws + 8388608);
  bf16*  BXd  = (bf16*) (ws + 12582912);
  float* L0m  = (float*)(ws + 16777216);   // [4096][256] fp32 = 4 MB
  float* L0d  = (float*)(ws + 20971520);
  float* L2nm = (float*)(ws + 25165824);
  float* L2nd = (float*)(ws + 29360128);
  float* Sbuf = (float*)(ws + 33554432);   // 1 MB
  float* bSbuf= (float*)(ws + 34603008);   // 4 KB
  float* scal = (float*)(ws + 34607104);   // 96 KB
  float* Scol = (float*)(ws + 34705408);   // 2 KB
  bf16*  Tm   = (bf16*) (ws + 34707456);   // 8 MB
  bf16*  Td   = (bf16*) (ws + 43096064);   // 8 MB (end 51,484,672)
  float* partial = (float*)(ws + 34707456); // 16 MB, ALIASES Tm/Td (dead after stage2)

  prep_kernel<<<256, 256, 0, stream>>>(m_co_deg, d_co_deg, m_d_degree, d_m_degree,
                                       Wx, bx, scal, Sbuf, bSbuf);
  stage1_kernel<<<dim3(64,16), 256, 0, stream>>>(m_d_feat, Wm, bm, Wd, bd, Sbuf, bSbuf, scal,
                                                 BHm, BHd, L0m, L0d, L2nm, L2nd, Tm, Td);
  stage2_kernel<<<8192, 256, 0, stream>>>(Tm, Td, central_m, central_d, BXm, BXd);
  colsum_kernel<<<512, 64, 0, stream>>>(BHm, BHd, Scol);
  zero_kernel<<<1024, 256, 0, stream>>>(partial);
  gemm_kernel<<<512, 256, 0, stream>>>(bigraph, m_co, d_co, central_m, central_d,
                                       scal, BHm, BHd, BXm, BXd, partial);
  reduce_kernel<<<2048, 256, 0, stream>>>(partial, L0m, L0d, L2nm, L2nd, Scol, scal, (float*)d_out);
}